// Round 3
// baseline (131.379 us; speedup 1.0000x reference)
//
#include <hip/hip_runtime.h>
#include <stdint.h>

// FaceWeightedFusion: B=4, H=W=1024, N=262144, all fp32 in/out.
// Erosion collapsed to capped L-inf distance transform (binary mask):
//   weight(p) = 0 (mask=0) | table[min(15,(d-1)/3)], table[k]=0.1+0.06k (k=15 -> 1.0)
// K1 row_dt: ballot zero-bitmaps + ctz/clz -> u8 row distances (cap 46).
//   R7: ballot results are wave-uniform, consumer is the same wave -> registers, no LDS.
// K2 col_dt: fast +-5 register window via v_pk_{max,min}_i16; ballot-guarded exact
//   fallback. Packs [0:19] depth*1048575, [20:24] bucket (31=mask0), [25] edge.
//   R8: writes TWO row-pair-interleaved copies of the packed image:
//     qE[k][x] = (row 2k, row 2k+1), qO[k][x] = (row 2k+1, row 2k+2)  (8B each)
//   so K3 fetches ALL FOUR bilinear corners with ONE parity-selected 16B load.
//   Strip-boundary qO halves are written by the neighboring strips (disjoint 4B
//   halves -> no race); qO[511].hi replicates row 1023.
// K3 sample4: 4 pts/thread, XCD-affinity (blockIdx%4==batch), ONE dwordx4 gather
//   per point (line-touches/point 2 -> ~1.1; K3 was concurrency*latency-bound).
// NOTE R5 lesson: do NOT fuse row into col — halo recompute cost ~7x the row work.
// NOTE R6 lesson: do NOT fuse the 3 dispatches into one cooperative kernel —
//   440us: coop+launch_bounds drove VGPR to 32 (scratch spill), uncapturable launch.
// NOTE: ~43us of dur_us is the harness's 256MiB ws re-poison fill (timed, fixed).
// ws: packed path 36 MB (rbuf 4 + qE 16 + qO 16). Fallback (<36MB): u8 bucket path.

#define HH 1024
#define WW 1024
#define HWIMG (HH * WW)
#define NPTS 262144

typedef short short2v __attribute__((ext_vector_type(2)));
typedef float f32x4 __attribute__((ext_vector_type(4)));
typedef uint32_t u32x2 __attribute__((ext_vector_type(2), aligned(8)));
typedef uint32_t u32x4a __attribute__((ext_vector_type(4), aligned(8)));

static __device__ __forceinline__ uint32_t umin_(uint32_t a, uint32_t b) { return a < b ? a : b; }

// ---------------- Kernel 1: row distance transform (capped 46) ----------------
__global__ __launch_bounds__(256) void row_dt_kernel(const float* __restrict__ mask,
                                                     uint8_t* __restrict__ rbuf) {
    const int l = threadIdx.x & 63;
    const int row = blockIdx.x * 4 + (threadIdx.x >> 6);   // b*1024 + y
    const float* mrow = mask + (size_t)row * WW;

    uint64_t bm[18];
    bm[0] = 0ull;
    bm[17] = 0ull;
#pragma unroll
    for (int i = 0; i < 16; ++i) {
        float m = mrow[i * 64 + l];
        bm[i + 1] = __ballot(m == 0.0f);
    }

    uint8_t* rrow = rbuf + (size_t)row * WW;
#pragma unroll
    for (int i = 0; i < 16; ++i) {
        uint64_t W0 = bm[i];
        uint64_t W1 = bm[i + 1];
        uint64_t W2 = bm[i + 2];
        uint64_t rmask = (W1 >> l) | ((W2 << 1) << (63 - l));
        uint64_t lmask = (W1 << (63 - l)) | ((W0 >> 1) >> l);
        int dr = rmask ? __builtin_ctzll(rmask) : 64;
        int dl = lmask ? __builtin_clzll(lmask) : 64;
        int d = dr < dl ? dr : dl;
        if (d > 46) d = 46;
        rrow[i * 64 + l] = (uint8_t)d;
    }
}

// ------------- Kernel 2: column envelope, +-5 fast window + pack -------------
template<bool PACK>
__global__ __launch_bounds__(256) void col_dt_kernel(const uint8_t* __restrict__ rbuf,
                                                     const float* __restrict__ edge,
                                                     const float* __restrict__ depth,
                                                     uint8_t* __restrict__ bucket_out,
                                                     uint32_t* __restrict__ qE,
                                                     uint32_t* __restrict__ qO) {
    const int bx = blockIdx.x;
    const int tx = bx & 15, ty = (bx >> 4) & 15, b = bx >> 8;
    const int x0 = tx * 64, y0 = ty * 64;
    const int c = threadIdx.x & 63;
    const int t = threadIdx.x >> 6;
    const int ybase = y0 + t * 16;
    const uint8_t* imgc = rbuf + (size_t)b * HWIMG + x0 + c;

    // Fast window: rows [ybase-4, ybase+19] as 12 (even,odd) i16 pairs.
    uint32_t wf[12];
#pragma unroll
    for (int j = 0; j < 12; ++j) {
        int r0 = ybase - 4 + 2 * j;
        int r1 = r0 + 1;
        int r0c = r0 < 0 ? 0 : (r0 > 1023 ? 1023 : r0);
        int r1c = r1 < 0 ? 0 : (r1 > 1023 ? 1023 : r1);
        uint32_t lo = imgc[(size_t)r0c * WW];      // coalesced 64B wave load
        uint32_t hi = imgc[(size_t)r1c * WW];
        if (r0 != r0c) lo = 46;                    // outside image: no zeros
        if (r1 != r1c) hi = 46;
        wf[j] = lo | (hi << 16);
    }

    uint32_t Dv[16];
    bool bad = false;
#pragma unroll
    for (int i = 0; i < 16; ++i) {
        const int base2 = i >> 1;
        const int par = i & 1;
        short2v D2 = (short2v){46, 46};
#pragma unroll
        for (int q = 0; q < 5; ++q) {              // covers dy in [-5,5] (by parity)
            int dy0 = 2 * q - 4 - par;             // compile-time
            short a0 = (short)(dy0 < 0 ? -dy0 : dy0);
            short a1 = (short)(dy0 + 1 < 0 ? -(dy0 + 1) : dy0 + 1);
            short2v A = (short2v){a0, a1};
            short2v v = __builtin_bit_cast(short2v, wf[base2 + q]);
            short2v mx = __builtin_elementwise_max(A, v);   // v_pk_max_i16
            D2 = __builtin_elementwise_min(D2, mx);         // v_pk_min_i16
        }
        uint32_t D = (uint32_t)(D2.x < D2.y ? D2.x : D2.y);
        Dv[i] = D;
        bad |= (D >= 6);       // excluded terms all >= 5 -> partial<=5 is exact
    }

    if (__ballot(bad) != 0) {  // exact fallback, register-light (P ~ 0 on real data)
#pragma unroll
        for (int i = 0; i < 16; ++i) {
            uint32_t D = 46;
            for (int dy = -46; dy <= 46; ++dy) {
                int y = ybase + i + dy;
                uint32_t r = 46;
                if (y >= 0 && y < HH) r = imgc[(size_t)y * WW];
                uint32_t a = (uint32_t)(dy < 0 ? -dy : dy);
                uint32_t m = a > r ? a : r;
                D = D < m ? D : m;
            }
            Dv[i] = D;
        }
    }

    if (PACK) {
        // Build the 16 packed words, then emit row-pair interleaved copies.
        uint32_t wv[16];
#pragma unroll
        for (int i = 0; i < 16; ++i) {
            uint32_t D = Dv[i];
            const size_t pix = (size_t)b * HWIMG + (size_t)(ybase + i) * WW + x0 + c;
            float dv = __builtin_nontemporal_load(&depth[pix]);
            float ev = __builtin_nontemporal_load(&edge[pix]);   // exactly 0.0f/1.0f
            uint32_t q20 = (uint32_t)fminf(rintf(dv * 1048575.0f), 1048575.0f);
            uint32_t bk = (D == 0) ? 31u : umin_(15u, (D - 1u) / 3u);
            wv[i] = q20 | (bk << 20) | ((ev != 0.0f ? 1u : 0u) << 25);
        }

        const int xcol = x0 + c;
        const size_t bq = (size_t)b * (HWIMG / 2);      // per-batch entries (u32x2)
        u32x2* qE2 = (u32x2*)qE;
        u32x2* qO2 = (u32x2*)qO;
        const int k0 = ybase >> 1;                      // first qE k-row of strip
        // qE: pairs (ybase+2a, ybase+2a+1), a=0..7 — fully owned, dense 8B stores.
#pragma unroll
        for (int a = 0; a < 8; ++a) {
            u32x2 pr2 = (u32x2){wv[2 * a], wv[2 * a + 1]};
            __builtin_nontemporal_store(pr2, &qE2[bq + (size_t)(k0 + a) * WW + xcol]);
        }
        // qO inner: pairs (ybase+2a+1, ybase+2a+2), a=0..6.
#pragma unroll
        for (int a = 0; a < 7; ++a) {
            u32x2 pr2 = (u32x2){wv[2 * a + 1], wv[2 * a + 2]};
            __builtin_nontemporal_store(pr2, &qO2[bq + (size_t)(k0 + a) * WW + xcol]);
        }
        // qO boundary halves (disjoint 4B halves of neighbor-strip entries).
        uint32_t* qOu = qO;
        const size_t bqu = (size_t)b * HWIMG;           // per-batch u32 elements
        if (ybase > 0) {                                // row ybase -> qO[k0-1].hi
            __builtin_nontemporal_store(wv[0], &qOu[bqu + ((size_t)(k0 - 1) * WW + xcol) * 2 + 1]);
        }
        // row ybase+15 -> qO[k0+7].lo
        __builtin_nontemporal_store(wv[15], &qOu[bqu + ((size_t)(k0 + 7) * WW + xcol) * 2]);
        if (ybase + 15 == 1023) {                       // replicate row 1023 -> qO[511].hi
            __builtin_nontemporal_store(wv[15], &qOu[bqu + ((size_t)(k0 + 7) * WW + xcol) * 2 + 1]);
        }
    } else {
#pragma unroll
        for (int i = 0; i < 16; ++i) {
            uint32_t D = Dv[i];
            const size_t pix = (size_t)b * HWIMG + (size_t)(ybase + i) * WW + x0 + c;
            uint8_t o = (D == 0) ? (uint8_t)255 : (uint8_t)umin_(15u, (D - 1u) / 3u);
            bucket_out[pix] = o;
        }
    }
}

// ---------------- Kernel 3: sampling, 4 points/thread, 1 gather/point ----------------
static __device__ __forceinline__ float decode_w5(uint32_t p) {
    uint32_t k = (p >> 20) & 31u;
    if (k == 31u) return 0.0f;
    float v = 0.1f + (float)k * 0.06f;
    return v < 1.0f ? v : 1.0f;
}

__global__ __launch_bounds__(256) void sample4_kernel(
    const uint32_t* __restrict__ qE, const uint32_t* __restrict__ qO,
    const float* __restrict__ xy,
    const float* __restrict__ z, const float* __restrict__ occ_body,
    const float* __restrict__ occ_face, float* __restrict__ out) {
    const int b = blockIdx.x & 3;            // XCD affinity: one 4MB image per XCD L2
    const int n0 = (blockIdx.x >> 2) * 1024 + threadIdx.x * 4;
    const size_t pb = (size_t)b * NPTS;

    f32x4 xv  = __builtin_nontemporal_load((const f32x4*)&xy[pb * 2 + n0]);
    f32x4 yv  = __builtin_nontemporal_load((const f32x4*)&xy[pb * 2 + NPTS + n0]);
    f32x4 zv  = __builtin_nontemporal_load((const f32x4*)&z[pb + n0]);
    f32x4 obv = __builtin_nontemporal_load((const f32x4*)&occ_body[pb + n0]);
    f32x4 ofv = __builtin_nontemporal_load((const f32x4*)&occ_face[pb + n0]);

    const size_t bimg = (size_t)b * HWIMG;   // per-batch u32 elements in qE/qO
    f32x4 res;
    const uint32_t* addr[4];
    int sel[4];
    float wgt[4][4];
#pragma unroll
    for (int j = 0; j < 4; ++j) {
        float fx = ((xv[j] + 1.0f) * 0.5f) * 1023.0f;
        float fy = ((yv[j] + 1.0f) * 0.5f) * 1023.0f;
        float x0f = floorf(fx), y0f = floorf(fy);
        float wx = fx - x0f, wy = fy - y0f;
        int x0i = (int)x0f; x0i = x0i < 0 ? 0 : (x0i > 1023 ? 1023 : x0i);
        int y0i = (int)y0f; y0i = y0i < 0 ? 0 : (y0i > 1023 ? 1023 : y0i);
        // x0i==1023 => wx==0 => x1 irrelevant; load pair at min(x0i,1022), sel shifts.
        int xl = x0i > 1022 ? 1022 : x0i;
        sel[j] = x0i - xl;                       // 0 or 1
        // Parity-selected row-pair image: k = y0i>>1 for both copies; the 16B at
        // [k][xl..xl+1] holds corners (y0,xl),(y1,xl),(y0,xl+1),(y1,xl+1).
        const uint32_t* base = (y0i & 1) ? qO : qE;
        addr[j] = base + bimg + ((size_t)(y0i >> 1) * WW + xl) * 2;
        wgt[j][0] = (1.0f - wx) * (1.0f - wy);
        wgt[j][1] = wx * (1.0f - wy);
        wgt[j][2] = (1.0f - wx) * wy;
        wgt[j][3] = wx * wy;
    }
    u32x4a pr[4];
#pragma unroll
    for (int j = 0; j < 4; ++j) {                // 4 independent dwordx4 gathers
        pr[j] = *(const u32x4a*)addr[j];
    }

#pragma unroll
    for (int j = 0; j < 4; ++j) {
        uint32_t p00 = sel[j] ? pr[j].z : pr[j].x;
        uint32_t p01 = pr[j].z;
        uint32_t p10 = sel[j] ? pr[j].w : pr[j].y;
        uint32_t p11 = pr[j].w;
        float e = (float)((p00 >> 25) & 1u) * wgt[j][0]
                + (float)((p01 >> 25) & 1u) * wgt[j][1]
                + (float)((p10 >> 25) & 1u) * wgt[j][2]
                + (float)((p11 >> 25) & 1u) * wgt[j][3];
        float w = 0.0f;
        if (e > 0.01f) {
            const float DQS = 1.0f / 1048575.0f;
            float dq = ((float)(p00 & 0xFFFFFu) * wgt[j][0]
                      + (float)(p01 & 0xFFFFFu) * wgt[j][1]
                      + (float)(p10 & 0xFFFFFu) * wgt[j][2]
                      + (float)(p11 & 0xFFFFFu) * wgt[j][3]) * DQS;
            float la = decode_w5(p00) * wgt[j][0] + decode_w5(p01) * wgt[j][1]
                     + decode_w5(p10) * wgt[j][2] + decode_w5(p11) * wgt[j][3];
            float ps = zv[j] - dq;
            w = expf(-(ps * ps) * 1000.0f) * la;
        }
        res[j] = w * ofv[j] + (1.0f - w) * obv[j];
    }
    __builtin_nontemporal_store(res, (f32x4*)&out[pb + n0]);
}

// ---------------- Fallback sample (tiny ws): 3-image scalar path ----------------
static __device__ __forceinline__ float decode_w8(uint32_t k) {
    if (k == 255u) return 0.0f;
    float v = 0.1f + (float)k * 0.06f;
    return v < 1.0f ? v : 1.0f;
}

__global__ __launch_bounds__(256) void sample_fallback_kernel(
    const float* __restrict__ edge_img, const float* __restrict__ depth_img,
    const uint8_t* __restrict__ wimg,
    const float* __restrict__ xy, const float* __restrict__ z,
    const float* __restrict__ occ_body, const float* __restrict__ occ_face,
    float* __restrict__ out) {
    const int b = blockIdx.x & 3;
    const int n = (blockIdx.x >> 2) * 256 + threadIdx.x;

    float x = xy[(size_t)b * 2 * NPTS + n];
    float y = xy[(size_t)b * 2 * NPTS + NPTS + n];
    float fx = ((x + 1.0f) * 0.5f) * 1023.0f;
    float fy = ((y + 1.0f) * 0.5f) * 1023.0f;
    float x0f = floorf(fx), y0f = floorf(fy);
    float wx = fx - x0f, wy = fy - y0f;
    int x0i = (int)x0f; x0i = x0i < 0 ? 0 : (x0i > 1023 ? 1023 : x0i);
    int y0i = (int)y0f; y0i = y0i < 0 ? 0 : (y0i > 1023 ? 1023 : y0i);
    int x1i = x0i + 1 > 1023 ? 1023 : x0i + 1;
    int y1i = y0i + 1 > 1023 ? 1023 : y0i + 1;

    const size_t base = (size_t)b * HWIMG;
    const size_t i00 = base + (size_t)y0i * WW + x0i;
    const size_t i01 = base + (size_t)y0i * WW + x1i;
    const size_t i10 = base + (size_t)y1i * WW + x0i;
    const size_t i11 = base + (size_t)y1i * WW + x1i;

    const float w00 = (1.0f - wx) * (1.0f - wy);
    const float w01 = wx * (1.0f - wy);
    const float w10 = (1.0f - wx) * wy;
    const float w11 = wx * wy;

    float zv = z[(size_t)b * NPTS + n];
    float ob = occ_body[(size_t)b * NPTS + n];
    float of = occ_face[(size_t)b * NPTS + n];

    float w = 0.0f;
    float e = edge_img[i00] * w00 + edge_img[i01] * w01
            + edge_img[i10] * w10 + edge_img[i11] * w11;
    if (e > 0.01f) {
        float dq = depth_img[i00] * w00 + depth_img[i01] * w01
                 + depth_img[i10] * w10 + depth_img[i11] * w11;
        float la = decode_w8(wimg[i00]) * w00 + decode_w8(wimg[i01]) * w01
                 + decode_w8(wimg[i10]) * w10 + decode_w8(wimg[i11]) * w11;
        float ps = zv - dq;
        w = expf(-(ps * ps) * 1000.0f) * la;
    }
    out[(size_t)b * NPTS + n] = w * of + (1.0f - w) * ob;
}

extern "C" void kernel_launch(void* const* d_in, const int* in_sizes, int n_in,
                              void* d_out, int out_size, void* d_ws, size_t ws_size,
                              hipStream_t stream) {
    const float* mask      = (const float*)d_in[0];
    const float* depth     = (const float*)d_in[1];
    const float* edge      = (const float*)d_in[2];
    const float* xy        = (const float*)d_in[3];
    const float* z         = (const float*)d_in[4];
    const float* occ_body  = (const float*)d_in[5];
    const float* occ_face  = (const float*)d_in[6];
    float* out = (float*)d_out;

    uint8_t* rbuf = (uint8_t*)d_ws;                          // 4 MB
    // rbuf 4MB + qE 16MB + qO 16MB
    const size_t need_packed = (size_t)4 * HWIMG * (1 + 4 + 4);  // 36 MB

    row_dt_kernel<<<1024, 256, 0, stream>>>(mask, rbuf);

    if (ws_size >= need_packed) {
        uint32_t* qE = (uint32_t*)(rbuf + (size_t)4 * HWIMG);    // 16 MB
        uint32_t* qO = qE + (size_t)4 * HWIMG;                   // 16 MB
        col_dt_kernel<true><<<1024, 256, 0, stream>>>(rbuf, edge, depth, nullptr, qE, qO);
        sample4_kernel<<<1024, 256, 0, stream>>>(qE, qO, xy, z, occ_body, occ_face, out);
    } else {
        uint8_t* wbuf = rbuf + (size_t)4 * HWIMG;            // 4 MB
        col_dt_kernel<false><<<1024, 256, 0, stream>>>(rbuf, edge, depth, wbuf, nullptr, nullptr);
        sample_fallback_kernel<<<4096, 256, 0, stream>>>(edge, depth, wbuf,
                                                         xy, z, occ_body, occ_face, out);
    }
}

// Round 4
// 126.692 us; speedup vs baseline: 1.0370x; 1.0370x over previous
//
#include <hip/hip_runtime.h>
#include <stdint.h>

// FaceWeightedFusion: B=4, H=W=1024, N=262144, all fp32 in/out.
// Erosion collapsed to capped L-inf distance transform (binary mask):
//   weight(p) = 0 (mask=0) | table[min(15,(d-1)/3)], table[k]=0.1+0.06k (k=15 -> 1.0)
// K1 row_dt: ballot zero-bitmaps + ctz/clz -> u8 row distances (cap 46).
//   R7: ballot results are wave-uniform, consumer is the same wave -> registers, no LDS.
// K2 col_dt: fast +-5 register window via v_pk_{max,min}_i16; ballot-guarded exact
//   fallback. Packs [0:19] depth*1048575, [20:24] bucket (31=mask0), [25] edge.
//   R9: ONE row-pair interleaved packed image (4MB/batch = fits one XCD L2):
//     qP[k][x] = (row 2k, row 2k+1) as 8B entries. Strips are 16-row aligned ->
//     8 dense 8B stores, no cross-strip boundary writes.
// K3 sample4: 4 pts/thread, XCD-affinity (blockIdx%4==batch). Per point TWO 16B
//   loads A=qP[kA][xl], B=qP[kB][xl], kB=kA+(y0&1) (clamped): even y0 -> B==A
//   (same line, free), odd y0 -> A.hi/B.lo rows. Avg 1.5 line-touches/point at
//   4MB working set (R7 was 2.0@4MB; R8's 1.0@8MB lost L2 residency -> neutral).
// NOTE R5 lesson: do NOT fuse row into col — halo recompute cost ~7x the row work.
// NOTE R6 lesson: do NOT fuse the 3 dispatches into one cooperative kernel —
//   440us: coop+launch_bounds drove VGPR to 32 (scratch spill), uncapturable launch.
// NOTE: ~41us of dur_us is the harness's 256MiB ws re-poison fill (timed, fixed).
// ws: packed path 20 MB (rbuf 4 + qP 16). Fallback (<20MB): u8 bucket path.

#define HH 1024
#define WW 1024
#define HWIMG (HH * WW)
#define NPTS 262144

typedef short short2v __attribute__((ext_vector_type(2)));
typedef float f32x4 __attribute__((ext_vector_type(4)));
typedef uint32_t u32x2 __attribute__((ext_vector_type(2), aligned(8)));
typedef uint32_t u32x4a __attribute__((ext_vector_type(4), aligned(8)));

static __device__ __forceinline__ uint32_t umin_(uint32_t a, uint32_t b) { return a < b ? a : b; }

// ---------------- Kernel 1: row distance transform (capped 46) ----------------
__global__ __launch_bounds__(256) void row_dt_kernel(const float* __restrict__ mask,
                                                     uint8_t* __restrict__ rbuf) {
    const int l = threadIdx.x & 63;
    const int row = blockIdx.x * 4 + (threadIdx.x >> 6);   // b*1024 + y
    const float* mrow = mask + (size_t)row * WW;

    uint64_t bm[18];
    bm[0] = 0ull;
    bm[17] = 0ull;
#pragma unroll
    for (int i = 0; i < 16; ++i) {
        float m = mrow[i * 64 + l];
        bm[i + 1] = __ballot(m == 0.0f);
    }

    uint8_t* rrow = rbuf + (size_t)row * WW;
#pragma unroll
    for (int i = 0; i < 16; ++i) {
        uint64_t W0 = bm[i];
        uint64_t W1 = bm[i + 1];
        uint64_t W2 = bm[i + 2];
        uint64_t rmask = (W1 >> l) | ((W2 << 1) << (63 - l));
        uint64_t lmask = (W1 << (63 - l)) | ((W0 >> 1) >> l);
        int dr = rmask ? __builtin_ctzll(rmask) : 64;
        int dl = lmask ? __builtin_clzll(lmask) : 64;
        int d = dr < dl ? dr : dl;
        if (d > 46) d = 46;
        rrow[i * 64 + l] = (uint8_t)d;
    }
}

// ------------- Kernel 2: column envelope, +-5 fast window + pack -------------
template<bool PACK>
__global__ __launch_bounds__(256) void col_dt_kernel(const uint8_t* __restrict__ rbuf,
                                                     const float* __restrict__ edge,
                                                     const float* __restrict__ depth,
                                                     uint8_t* __restrict__ bucket_out,
                                                     uint32_t* __restrict__ qP) {
    const int bx = blockIdx.x;
    const int tx = bx & 15, ty = (bx >> 4) & 15, b = bx >> 8;
    const int x0 = tx * 64, y0 = ty * 64;
    const int c = threadIdx.x & 63;
    const int t = threadIdx.x >> 6;
    const int ybase = y0 + t * 16;
    const uint8_t* imgc = rbuf + (size_t)b * HWIMG + x0 + c;

    // Fast window: rows [ybase-4, ybase+19] as 12 (even,odd) i16 pairs.
    uint32_t wf[12];
#pragma unroll
    for (int j = 0; j < 12; ++j) {
        int r0 = ybase - 4 + 2 * j;
        int r1 = r0 + 1;
        int r0c = r0 < 0 ? 0 : (r0 > 1023 ? 1023 : r0);
        int r1c = r1 < 0 ? 0 : (r1 > 1023 ? 1023 : r1);
        uint32_t lo = imgc[(size_t)r0c * WW];      // coalesced 64B wave load
        uint32_t hi = imgc[(size_t)r1c * WW];
        if (r0 != r0c) lo = 46;                    // outside image: no zeros
        if (r1 != r1c) hi = 46;
        wf[j] = lo | (hi << 16);
    }

    uint32_t Dv[16];
    bool bad = false;
#pragma unroll
    for (int i = 0; i < 16; ++i) {
        const int base2 = i >> 1;
        const int par = i & 1;
        short2v D2 = (short2v){46, 46};
#pragma unroll
        for (int q = 0; q < 5; ++q) {              // covers dy in [-5,5] (by parity)
            int dy0 = 2 * q - 4 - par;             // compile-time
            short a0 = (short)(dy0 < 0 ? -dy0 : dy0);
            short a1 = (short)(dy0 + 1 < 0 ? -(dy0 + 1) : dy0 + 1);
            short2v A = (short2v){a0, a1};
            short2v v = __builtin_bit_cast(short2v, wf[base2 + q]);
            short2v mx = __builtin_elementwise_max(A, v);   // v_pk_max_i16
            D2 = __builtin_elementwise_min(D2, mx);         // v_pk_min_i16
        }
        uint32_t D = (uint32_t)(D2.x < D2.y ? D2.x : D2.y);
        Dv[i] = D;
        bad |= (D >= 6);       // excluded terms all >= 5 -> partial<=5 is exact
    }

    if (__ballot(bad) != 0) {  // exact fallback, register-light (P ~ 0 on real data)
#pragma unroll
        for (int i = 0; i < 16; ++i) {
            uint32_t D = 46;
            for (int dy = -46; dy <= 46; ++dy) {
                int y = ybase + i + dy;
                uint32_t r = 46;
                if (y >= 0 && y < HH) r = imgc[(size_t)y * WW];
                uint32_t a = (uint32_t)(dy < 0 ? -dy : dy);
                uint32_t m = a > r ? a : r;
                D = D < m ? D : m;
            }
            Dv[i] = D;
        }
    }

    if (PACK) {
        // Build the 16 packed words, then emit row-pair interleaved entries.
        uint32_t wv[16];
#pragma unroll
        for (int i = 0; i < 16; ++i) {
            uint32_t D = Dv[i];
            const size_t pix = (size_t)b * HWIMG + (size_t)(ybase + i) * WW + x0 + c;
            float dv = __builtin_nontemporal_load(&depth[pix]);
            float ev = __builtin_nontemporal_load(&edge[pix]);   // exactly 0.0f/1.0f
            uint32_t q20 = (uint32_t)fminf(rintf(dv * 1048575.0f), 1048575.0f);
            uint32_t bk = (D == 0) ? 31u : umin_(15u, (D - 1u) / 3u);
            wv[i] = q20 | (bk << 20) | ((ev != 0.0f ? 1u : 0u) << 25);
        }

        const int xcol = x0 + c;
        const size_t bq = (size_t)b * (HWIMG / 2);      // per-batch entries (u32x2)
        u32x2* qP2 = (u32x2*)qP;
        const int k0 = ybase >> 1;                      // strip is 16-row aligned
        // entry k0+a = (row ybase+2a, row ybase+2a+1): dense, fully owned.
#pragma unroll
        for (int a = 0; a < 8; ++a) {
            u32x2 pr2 = (u32x2){wv[2 * a], wv[2 * a + 1]};
            __builtin_nontemporal_store(pr2, &qP2[bq + (size_t)(k0 + a) * WW + xcol]);
        }
    } else {
#pragma unroll
        for (int i = 0; i < 16; ++i) {
            uint32_t D = Dv[i];
            const size_t pix = (size_t)b * HWIMG + (size_t)(ybase + i) * WW + x0 + c;
            uint8_t o = (D == 0) ? (uint8_t)255 : (uint8_t)umin_(15u, (D - 1u) / 3u);
            bucket_out[pix] = o;
        }
    }
}

// ---------------- Kernel 3: sampling, 4 points/thread, A/B pair gathers ----------------
static __device__ __forceinline__ float decode_w5(uint32_t p) {
    uint32_t k = (p >> 20) & 31u;
    if (k == 31u) return 0.0f;
    float v = 0.1f + (float)k * 0.06f;
    return v < 1.0f ? v : 1.0f;
}

__global__ __launch_bounds__(256) void sample4_kernel(
    const uint32_t* __restrict__ qP, const float* __restrict__ xy,
    const float* __restrict__ z, const float* __restrict__ occ_body,
    const float* __restrict__ occ_face, float* __restrict__ out) {
    const int b = blockIdx.x & 3;            // XCD affinity: one 4MB image per XCD L2
    const int n0 = (blockIdx.x >> 2) * 1024 + threadIdx.x * 4;
    const size_t pb = (size_t)b * NPTS;

    f32x4 xv  = __builtin_nontemporal_load((const f32x4*)&xy[pb * 2 + n0]);
    f32x4 yv  = __builtin_nontemporal_load((const f32x4*)&xy[pb * 2 + NPTS + n0]);
    f32x4 zv  = __builtin_nontemporal_load((const f32x4*)&z[pb + n0]);
    f32x4 obv = __builtin_nontemporal_load((const f32x4*)&occ_body[pb + n0]);
    f32x4 ofv = __builtin_nontemporal_load((const f32x4*)&occ_face[pb + n0]);

    const size_t bimg = (size_t)b * HWIMG;   // per-batch u32 elements in qP
    f32x4 res;
    const uint32_t* addrA[4];
    const uint32_t* addrB[4];
    int sel[4], par[4];
    float wgt[4][4];
#pragma unroll
    for (int j = 0; j < 4; ++j) {
        float fx = ((xv[j] + 1.0f) * 0.5f) * 1023.0f;
        float fy = ((yv[j] + 1.0f) * 0.5f) * 1023.0f;
        float x0f = floorf(fx), y0f = floorf(fy);
        float wx = fx - x0f, wy = fy - y0f;
        int x0i = (int)x0f; x0i = x0i < 0 ? 0 : (x0i > 1023 ? 1023 : x0i);
        int y0i = (int)y0f; y0i = y0i < 0 ? 0 : (y0i > 1023 ? 1023 : y0i);
        // x0i==1023 => wx==0 => x1 irrelevant; load pair at min(x0i,1022), sel shifts.
        int xl = x0i > 1022 ? 1022 : x0i;
        sel[j] = x0i - xl;                       // 0 or 1
        par[j] = y0i & 1;
        int kA = y0i >> 1;
        int kB = kA + par[j]; kB = kB > 511 ? 511 : kB;   // y0=1023: wy==0, B row moot
        addrA[j] = qP + bimg + ((size_t)kA * WW + xl) * 2;
        addrB[j] = qP + bimg + ((size_t)kB * WW + xl) * 2;
        wgt[j][0] = (1.0f - wx) * (1.0f - wy);
        wgt[j][1] = wx * (1.0f - wy);
        wgt[j][2] = (1.0f - wx) * wy;
        wgt[j][3] = wx * wy;
    }
    u32x4a prA[4], prB[4];
#pragma unroll
    for (int j = 0; j < 4; ++j) {                // 8 independent dwordx4 gathers
        prA[j] = *(const u32x4a*)addrA[j];       // even y0: B==A -> same line, free
        prB[j] = *(const u32x4a*)addrB[j];
    }

#pragma unroll
    for (int j = 0; j < 4; ++j) {
        // y0 row pair (xl, xl+1) from A; y1 row pair from B.
        uint32_t q00 = par[j] ? prA[j].y : prA[j].x;
        uint32_t q01 = par[j] ? prA[j].w : prA[j].z;
        uint32_t q10 = par[j] ? prB[j].x : prB[j].y;
        uint32_t q11 = par[j] ? prB[j].z : prB[j].w;
        uint32_t p00 = sel[j] ? q01 : q00;
        uint32_t p01 = q01;
        uint32_t p10 = sel[j] ? q11 : q10;
        uint32_t p11 = q11;
        float e = (float)((p00 >> 25) & 1u) * wgt[j][0]
                + (float)((p01 >> 25) & 1u) * wgt[j][1]
                + (float)((p10 >> 25) & 1u) * wgt[j][2]
                + (float)((p11 >> 25) & 1u) * wgt[j][3];
        float w = 0.0f;
        if (e > 0.01f) {
            const float DQS = 1.0f / 1048575.0f;
            float dq = ((float)(p00 & 0xFFFFFu) * wgt[j][0]
                      + (float)(p01 & 0xFFFFFu) * wgt[j][1]
                      + (float)(p10 & 0xFFFFFu) * wgt[j][2]
                      + (float)(p11 & 0xFFFFFu) * wgt[j][3]) * DQS;
            float la = decode_w5(p00) * wgt[j][0] + decode_w5(p01) * wgt[j][1]
                     + decode_w5(p10) * wgt[j][2] + decode_w5(p11) * wgt[j][3];
            float ps = zv[j] - dq;
            w = expf(-(ps * ps) * 1000.0f) * la;
        }
        res[j] = w * ofv[j] + (1.0f - w) * obv[j];
    }
    __builtin_nontemporal_store(res, (f32x4*)&out[pb + n0]);
}

// ---------------- Fallback sample (tiny ws): 3-image scalar path ----------------
static __device__ __forceinline__ float decode_w8(uint32_t k) {
    if (k == 255u) return 0.0f;
    float v = 0.1f + (float)k * 0.06f;
    return v < 1.0f ? v : 1.0f;
}

__global__ __launch_bounds__(256) void sample_fallback_kernel(
    const float* __restrict__ edge_img, const float* __restrict__ depth_img,
    const uint8_t* __restrict__ wimg,
    const float* __restrict__ xy, const float* __restrict__ z,
    const float* __restrict__ occ_body, const float* __restrict__ occ_face,
    float* __restrict__ out) {
    const int b = blockIdx.x & 3;
    const int n = (blockIdx.x >> 2) * 256 + threadIdx.x;

    float x = xy[(size_t)b * 2 * NPTS + n];
    float y = xy[(size_t)b * 2 * NPTS + NPTS + n];
    float fx = ((x + 1.0f) * 0.5f) * 1023.0f;
    float fy = ((y + 1.0f) * 0.5f) * 1023.0f;
    float x0f = floorf(fx), y0f = floorf(fy);
    float wx = fx - x0f, wy = fy - y0f;
    int x0i = (int)x0f; x0i = x0i < 0 ? 0 : (x0i > 1023 ? 1023 : x0i);
    int y0i = (int)y0f; y0i = y0i < 0 ? 0 : (y0i > 1023 ? 1023 : y0i);
    int x1i = x0i + 1 > 1023 ? 1023 : x0i + 1;
    int y1i = y0i + 1 > 1023 ? 1023 : y0i + 1;

    const size_t base = (size_t)b * HWIMG;
    const size_t i00 = base + (size_t)y0i * WW + x0i;
    const size_t i01 = base + (size_t)y0i * WW + x1i;
    const size_t i10 = base + (size_t)y1i * WW + x0i;
    const size_t i11 = base + (size_t)y1i * WW + x1i;

    const float w00 = (1.0f - wx) * (1.0f - wy);
    const float w01 = wx * (1.0f - wy);
    const float w10 = (1.0f - wx) * wy;
    const float w11 = wx * wy;

    float zv = z[(size_t)b * NPTS + n];
    float ob = occ_body[(size_t)b * NPTS + n];
    float of = occ_face[(size_t)b * NPTS + n];

    float w = 0.0f;
    float e = edge_img[i00] * w00 + edge_img[i01] * w01
            + edge_img[i10] * w10 + edge_img[i11] * w11;
    if (e > 0.01f) {
        float dq = depth_img[i00] * w00 + depth_img[i01] * w01
                 + depth_img[i10] * w10 + depth_img[i11] * w11;
        float la = decode_w8(wimg[i00]) * w00 + decode_w8(wimg[i01]) * w01
                 + decode_w8(wimg[i10]) * w10 + decode_w8(wimg[i11]) * w11;
        float ps = zv - dq;
        w = expf(-(ps * ps) * 1000.0f) * la;
    }
    out[(size_t)b * NPTS + n] = w * of + (1.0f - w) * ob;
}

extern "C" void kernel_launch(void* const* d_in, const int* in_sizes, int n_in,
                              void* d_out, int out_size, void* d_ws, size_t ws_size,
                              hipStream_t stream) {
    const float* mask      = (const float*)d_in[0];
    const float* depth     = (const float*)d_in[1];
    const float* edge      = (const float*)d_in[2];
    const float* xy        = (const float*)d_in[3];
    const float* z         = (const float*)d_in[4];
    const float* occ_body  = (const float*)d_in[5];
    const float* occ_face  = (const float*)d_in[6];
    float* out = (float*)d_out;

    uint8_t* rbuf = (uint8_t*)d_ws;                          // 4 MB
    // rbuf 4MB + qP 16MB
    const size_t need_packed = (size_t)4 * HWIMG * (1 + 4);  // 20 MB

    row_dt_kernel<<<1024, 256, 0, stream>>>(mask, rbuf);

    if (ws_size >= need_packed) {
        uint32_t* qP = (uint32_t*)(rbuf + (size_t)4 * HWIMG);    // 16 MB
        col_dt_kernel<true><<<1024, 256, 0, stream>>>(rbuf, edge, depth, nullptr, qP);
        sample4_kernel<<<1024, 256, 0, stream>>>(qP, xy, z, occ_body, occ_face, out);
    } else {
        uint8_t* wbuf = rbuf + (size_t)4 * HWIMG;            // 4 MB
        col_dt_kernel<false><<<1024, 256, 0, stream>>>(rbuf, edge, depth, wbuf, nullptr);
        sample_fallback_kernel<<<4096, 256, 0, stream>>>(edge, depth, wbuf,
                                                         xy, z, occ_body, occ_face, out);
    }
}